// Round 3
// baseline (228.823 us; speedup 1.0000x reference)
//
#include <hip/hip_runtime.h>

typedef unsigned short u16;
typedef unsigned int   u32;
typedef __attribute__((ext_vector_type(4))) float  f32x4;
typedef __attribute__((ext_vector_type(8))) __bf16 bf16x8;

#define RPB   1024
#define ITERS 16
#define HSTRF 68          // f32 transpose row stride (floats): 272B, bank-rotating, 16B-aligned
#define HSTR  72          // bf16 transpose row stride (u16): 144B
#define SMEM_BYTES 100096

__device__ __forceinline__ u32 pkbf(float a, float b){
  u16 ua = __builtin_bit_cast(u16, (__bf16)a);
  u16 ub = __builtin_bit_cast(u16, (__bf16)b);
  return (u32)ua | ((u32)ub << 16);
}
__device__ __forceinline__ u32 pk2(__bf16 a, __bf16 b){
  return (u32)__builtin_bit_cast(u16, a) | ((u32)__builtin_bit_cast(u16, b) << 16);
}
__device__ __forceinline__ bf16x8 ldfrag(const u16* base, int idx){
  return __builtin_bit_cast(bf16x8, *(const uint4*)(base + (size_t)idx * 8));
}
__device__ __forceinline__ bf16x8 cvt8(float4 a, float4 b){
  uint4 u;
  u.x = pkbf(a.x, a.y); u.y = pkbf(a.z, a.w);
  u.z = pkbf(b.x, b.y); u.w = pkbf(b.z, b.w);
  return __builtin_bit_cast(bf16x8, u);
}
__device__ __forceinline__ f32x4 mfma16(bf16x8 a, bf16x8 b, f32x4 c){
  return __builtin_amdgcn_mfma_f32_16x16x32_bf16(a, b, c, 0, 0, 0);
}
// exact 3-way bf16 split of 8 f32 (residual < 2^-25 rel)
__device__ __forceinline__ void split8(float4 a, float4 b, bf16x8* out){
  float x[8] = {a.x, a.y, a.z, a.w, b.x, b.y, b.z, b.w};
  bf16x8 l0, l1, l2;
  #pragma unroll
  for (int j = 0; j < 8; ++j){
    float v = x[j];
    __bf16 p0 = (__bf16)v; float r = v - (float)p0;   // exact (Sterbenz)
    __bf16 p1 = (__bf16)r; r = r - (float)p1;         // exact
    __bf16 p2 = (__bf16)r;
    l0[j] = p0; l1[j] = p1; l2[j] = p2;
  }
  out[0] = l0; out[1] = l1; out[2] = l2;
}
// high-precision 16(units)x16(rows) tile: 2 k-chunks x 6-term bf16x3 = 12 MFMA
__device__ __forceinline__ f32x4 hp_tile(const u16* w0, const u16* w1, const u16* w2,
                                         int mt, int lane, const bf16x8* B0, const bf16x8* B1){
  f32x4 c = {0.f, 0.f, 0.f, 0.f};
  const int f0 = (mt*2+0)*64 + lane, f1 = (mt*2+1)*64 + lane;
  bf16x8 A0 = ldfrag(w0, f0), A1 = ldfrag(w1, f0), A2 = ldfrag(w2, f0);
  c = mfma16(A0, B0[0], c); c = mfma16(A0, B0[1], c); c = mfma16(A1, B0[0], c);
  c = mfma16(A0, B0[2], c); c = mfma16(A1, B0[1], c); c = mfma16(A2, B0[0], c);
  A0 = ldfrag(w0, f1); A1 = ldfrag(w1, f1); A2 = ldfrag(w2, f1);
  c = mfma16(A0, B1[0], c); c = mfma16(A0, B1[1], c); c = mfma16(A1, B1[0], c);
  c = mfma16(A0, B1[2], c); c = mfma16(A1, B1[1], c); c = mfma16(A2, B1[0], c);
  return c;
}

// M = feature dim (A = weights, LDS), N = batch rows (B = activations).
// A: A[m=lane&15][k=(lane>>4)*8+j]; C/D: n=lane&15, m=(lane>>4)*4+r.
__global__ __launch_bounds__(256, 1) void ode_fused(
    const float* __restrict__ tptr, const float* __restrict__ z, const float* __restrict__ e,
    const float* __restrict__ W0p, const float* __restrict__ b0p,
    const float* __restrict__ W1p, const float* __restrict__ b1p,
    const float* __restrict__ W2p, const float* __restrict__ b2p,
    float* __restrict__ out, long long Btot)
{
  extern __shared__ __align__(16) char smem[];
  u16*   wf3  = (u16*)smem;                 // [2][3][4096] fwd L0/L1 A-frags, 3 levels
  u16*   wf2  = wf3 + 6*4096;               // [4096] fwd L2 A-frags (single bf16)
  u16*   wb   = wf2 + 4096;                 // [3][4096] bwd A-frags (single bf16)
  float* bias = (float*)(wb + 3*4096);      // [3][64]  b_eff = b + t*W[:,0]
  float* hbuf = bias + 192;                 // [4][16*HSTRF] per-wave transpose buffer

  const int tid = threadIdx.x;
  const float tf = tptr[0];
  const float* Ws[3] = {W0p, W1p, W2p};
  const float* bs[3] = {b0p, b1p, b2p};

  // ---- stage weight fragments ----
  for (int L = 0; L < 3; ++L){
    const float* W = Ws[L];
    for (int eidx = tid; eidx < 512; eidx += 256){
      const int l = eidx & 63, km = eidx >> 6;
      const int mt = km >> 1, kc = km & 1;
      const int n15 = l & 15, q = l >> 4;
      { // forward A[m][k] = W[m][k+1], 8 contiguous along W row
        const float* p = W + (mt*16 + n15)*65 + 1 + kc*32 + q*8;
        if (L < 2){
          uint4 u0, u1, u2;
          u32* d0 = (u32*)&u0; u32* d1 = (u32*)&u1; u32* d2 = (u32*)&u2;
          #pragma unroll
          for (int h = 0; h < 4; ++h){
            __bf16 a0, a1, a2, b0_, b1_, b2_;
            float v = p[2*h];
            a0 = (__bf16)v; float r = v - (float)a0;
            a1 = (__bf16)r; r = r - (float)a1; a2 = (__bf16)r;
            v = p[2*h+1];
            b0_ = (__bf16)v; r = v - (float)b0_;
            b1_ = (__bf16)r; r = r - (float)b1_; b2_ = (__bf16)r;
            d0[h] = pk2(a0, b0_); d1[h] = pk2(a1, b1_); d2[h] = pk2(a2, b2_);
          }
          *(uint4*)(&wf3[(L*3+0)*4096 + eidx*8]) = u0;
          *(uint4*)(&wf3[(L*3+1)*4096 + eidx*8]) = u1;
          *(uint4*)(&wf3[(L*3+2)*4096 + eidx*8]) = u2;
        } else {
          uint4 u;
          u.x = pkbf(p[0], p[1]); u.y = pkbf(p[2], p[3]);
          u.z = pkbf(p[4], p[5]); u.w = pkbf(p[6], p[7]);
          *(uint4*)(&wf2[eidx*8]) = u;
        }
      }
      { // backward A[m][k] = W[k][m+1], column walk stride 65
        const float* p = W + (kc*32 + q*8)*65 + mt*16 + n15 + 1;
        uint4 u;
        u.x = pkbf(p[0],   p[65]);  u.y = pkbf(p[130], p[195]);
        u.z = pkbf(p[260], p[325]); u.w = pkbf(p[390], p[455]);
        *(uint4*)(&wb[L*4096 + eidx*8]) = u;
      }
    }
  }
  if (tid < 192){
    const int L = tid >> 6, m = tid & 63;
    bias[L*64 + m] = bs[L][m] + tf * Ws[L][m*65];
  }
  __syncthreads();

  const int wave = tid >> 6, lane = tid & 63;
  const int n = lane & 15, q = lane >> 4;
  float* hbF = hbuf + wave*16*HSTRF;
  float* hwF = hbF + n*HSTRF + q*4;           // f32 transpose write (+ mt*16)
  const float* hrF = hbF + n*HSTRF + q*8;     // f32 transpose read  (+ kc*32, two float4)
  u16* hbU = (u16*)hbF;                        // bf16 view of same buffer
  u16* hwU = hbU + n*HSTR + q*4;
  const u16* hrU = hbU + n*HSTR + q*8;

  for (int it = 0; it < ITERS; ++it){
    const int r0 = blockIdx.x*RPB + (it*4 + wave)*16;
    const size_t row = (size_t)(r0 + n);

    const float4* zr = (const float4*)(z + row*64);
    bf16x8 zB0[3], zB1[3];
    split8(zr[2*q],     zr[2*q + 1], zB0);
    split8(zr[8 + 2*q], zr[9 + 2*q], zB1);

    // ---------- forward layer 0 (high precision) ----------
    f32x4 h0[4];
    #pragma unroll
    for (int mt = 0; mt < 4; ++mt){
      f32x4 c = hp_tile(&wf3[0], &wf3[4096], &wf3[2*4096], mt, lane, zB0, zB1);
      const f32x4 bv = *(const f32x4*)(&bias[0*64 + mt*16 + q*4]);
      #pragma unroll
      for (int r = 0; r < 4; ++r){
        float v = c[r] + bv[r];
        h0[mt][r] = v > 0.f ? v : 0.f;
      }
    }
    #pragma unroll
    for (int mt = 0; mt < 4; ++mt)
      *(float4*)(hwF + mt*16) = __builtin_bit_cast(float4, h0[mt]);
    __syncthreads();
    bf16x8 h0B0[3], h0B1[3];
    split8(*(const float4*)(hrF),      *(const float4*)(hrF + 4),  h0B0);
    split8(*(const float4*)(hrF + 32), *(const float4*)(hrF + 36), h0B1);

    // ---------- forward layer 1 (high precision) ----------
    f32x4 h1[4];
    #pragma unroll
    for (int mt = 0; mt < 4; ++mt){
      f32x4 c = hp_tile(&wf3[3*4096], &wf3[4*4096], &wf3[5*4096], mt, lane, h0B0, h0B1);
      const f32x4 bv = *(const f32x4*)(&bias[1*64 + mt*16 + q*4]);
      #pragma unroll
      for (int r = 0; r < 4; ++r){
        float v = c[r] + bv[r];
        h1[mt][r] = v > 0.f ? v : 0.f;
      }
    }
    __syncthreads();   // protect f32 buffer reads before bf16 overwrite (paranoia; per-wave buffer)
    #pragma unroll
    for (int mt = 0; mt < 4; ++mt){
      uint2 w; w.x = pkbf(h1[mt][0], h1[mt][1]); w.y = pkbf(h1[mt][2], h1[mt][3]);
      *(uint2*)(hwU + mt*16) = w;
    }
    __syncthreads();
    const bf16x8 h1b0 = __builtin_bit_cast(bf16x8, *(const uint4*)(hrU));
    const bf16x8 h1b1 = __builtin_bit_cast(bf16x8, *(const uint4*)(hrU + 32));

    // ---------- forward layer 2 + store z_dot ----------
    #pragma unroll
    for (int mt = 0; mt < 4; ++mt){
      f32x4 c = {0.f, 0.f, 0.f, 0.f};
      c = mfma16(ldfrag(wf2, (mt*2+0)*64 + lane), h1b0, c);
      c = mfma16(ldfrag(wf2, (mt*2+1)*64 + lane), h1b1, c);
      const f32x4 bv = *(const f32x4*)(&bias[2*64 + mt*16 + q*4]);
      float4 w;
      w.x = c[0] + bv[0]; w.y = c[1] + bv[1];
      w.z = c[2] + bv[2]; w.w = c[3] + bv[3];
      *(float4*)(out + row*64 + mt*16 + q*4) = w;
    }

    // ---------- backward (plain bf16; masks from f32 h0/h1) ----------
    const float4* er = (const float4*)(e + row*64);
    const bf16x8 eb0 = cvt8(er[2*q],     er[2*q + 1]);
    const bf16x8 eb1 = cvt8(er[8 + 2*q], er[9 + 2*q]);

    f32x4 g1[4];
    #pragma unroll
    for (int mt = 0; mt < 4; ++mt){
      f32x4 c = {0.f, 0.f, 0.f, 0.f};
      c = mfma16(ldfrag(&wb[2*4096], (mt*2+0)*64 + lane), eb0, c);
      c = mfma16(ldfrag(&wb[2*4096], (mt*2+1)*64 + lane), eb1, c);
      #pragma unroll
      for (int r = 0; r < 4; ++r)
        g1[mt][r] = (h1[mt][r] > 0.f) ? c[r] : 0.f;
    }
    #pragma unroll
    for (int mt = 0; mt < 4; ++mt){
      uint2 w; w.x = pkbf(g1[mt][0], g1[mt][1]); w.y = pkbf(g1[mt][2], g1[mt][3]);
      *(uint2*)(hwU + mt*16) = w;
    }
    __syncthreads();
    const bf16x8 g1b0 = __builtin_bit_cast(bf16x8, *(const uint4*)(hrU));
    const bf16x8 g1b1 = __builtin_bit_cast(bf16x8, *(const uint4*)(hrU + 32));

    f32x4 g0[4];
    #pragma unroll
    for (int mt = 0; mt < 4; ++mt){
      f32x4 c = {0.f, 0.f, 0.f, 0.f};
      c = mfma16(ldfrag(&wb[1*4096], (mt*2+0)*64 + lane), g1b0, c);
      c = mfma16(ldfrag(&wb[1*4096], (mt*2+1)*64 + lane), g1b1, c);
      #pragma unroll
      for (int r = 0; r < 4; ++r)
        g0[mt][r] = (h0[mt][r] > 0.f) ? c[r] : 0.f;
    }
    #pragma unroll
    for (int mt = 0; mt < 4; ++mt){
      uint2 w; w.x = pkbf(g0[mt][0], g0[mt][1]); w.y = pkbf(g0[mt][2], g0[mt][3]);
      *(uint2*)(hwU + mt*16) = w;
    }
    __syncthreads();
    const bf16x8 g0b0 = __builtin_bit_cast(bf16x8, *(const uint4*)(hrU));
    const bf16x8 g0b1 = __builtin_bit_cast(bf16x8, *(const uint4*)(hrU + 32));

    float s = 0.f;
    #pragma unroll
    for (int mt = 0; mt < 4; ++mt){
      f32x4 c = {0.f, 0.f, 0.f, 0.f};
      c = mfma16(ldfrag(&wb[0], (mt*2+0)*64 + lane), g0b0, c);
      c = mfma16(ldfrag(&wb[0], (mt*2+1)*64 + lane), g0b1, c);
      const float4 ec = *(const float4*)(e + row*64 + mt*16 + q*4);
      s += c[0]*ec.x + c[1]*ec.y + c[2]*ec.z + c[3]*ec.w;
    }
    s += __shfl_xor(s, 16, 64);
    s += __shfl_xor(s, 32, 64);
    if (lane < 16)
      out[(size_t)Btot*64 + r0 + lane] = -s;
  }
}

extern "C" void kernel_launch(void* const* d_in, const int* in_sizes, int n_in,
                              void* d_out, int out_size, void* d_ws, size_t ws_size,
                              hipStream_t stream){
  const float* t  = (const float*)d_in[0];
  const float* z  = (const float*)d_in[1];
  const float* e  = (const float*)d_in[2];
  const float* W0 = (const float*)d_in[3];
  const float* b0 = (const float*)d_in[4];
  const float* W1 = (const float*)d_in[5];
  const float* b1 = (const float*)d_in[6];
  const float* W2 = (const float*)d_in[7];
  const float* b2 = (const float*)d_in[8];
  float* out = (float*)d_out;
  const long long B = (long long)in_sizes[1] / 64;   // 262144
  const int grid = (int)(B / RPB);                   // 256
  ode_fused<<<grid, 256, SMEM_BYTES, stream>>>(t, z, e, W0, b0, W1, b1, W2, b2, out, B);
}